// Round 4
// baseline (136.249 us; speedup 1.0000x reference)
//
#include <hip/hip_runtime.h>
#include <hip/hip_bf16.h>

#define N_NODES 8192
#define FIN 512
#define FOUT 64
#define LRELU_ALPHA 0.2f
#define SLAB 512
#define NSLAB (N_NODES / SLAB)   // 16

typedef __attribute__((ext_vector_type(8))) short short8;
typedef __attribute__((ext_vector_type(4))) float floatx4;

static __device__ __forceinline__ short f2bf_bits(float x) {
    union { __hip_bfloat16 b; short s; } u; u.b = __float2bfloat16(x); return u.s;
}

// p = adj>0 ? exp(leakyrelu(ssrc + sdst)) : 0   (a_b folded into ssrc)
static __device__ __forceinline__ float pval(float ssrc, float sd, int adjv) {
    float e = ssrc + sd;
    e = fmaxf(e, LRELU_ALPHA * e);
    float pv = __expf(e);
    return adjv > 0 ? pv : 0.0f;
}

// Kernel A: h = x@W + b; s_src = h@a[:64] + a_b; s_dst = h@a[64:];
// hswz = bf16(h)^T in MFMA-B-fragment-major layout:
//   hswz[((ks*4 + n)*64 + lane)*8 + e] = h[j = ks*32 + (lane>>4)*8 + e][f = n*16 + (lane&15)]
// One wave computes 8 rows (r0 = 8-aligned), so the store is one short8 per lane.
__global__ __launch_bounds__(256) void gat_h(
    const float* __restrict__ x, const float* __restrict__ W,
    const float* __restrict__ bias, const float* __restrict__ a,
    const float* __restrict__ a_b,
    float* __restrict__ s_src, float* __restrict__ s_dst,
    unsigned short* __restrict__ hswz)
{
    const int lane = threadIdx.x & 63;
    const int wave = threadIdx.x >> 6;
    const int r0 = (blockIdx.x * 4 + wave) * 8;   // 8 rows per wave

    float acc[8] = {0.f,0.f,0.f,0.f,0.f,0.f,0.f,0.f};
    const float* x0 = x + (size_t)r0 * FIN;

    #pragma unroll 2
    for (int k = 0; k < FIN; k += 4) {
        float w0 = W[(k + 0) * FOUT + lane];
        float w1 = W[(k + 1) * FOUT + lane];
        float w2 = W[(k + 2) * FOUT + lane];
        float w3 = W[(k + 3) * FOUT + lane];
        #pragma unroll
        for (int rr = 0; rr < 8; ++rr) {
            float4 xv = *reinterpret_cast<const float4*>(x0 + (size_t)rr * FIN + k);
            acc[rr] = fmaf(xv.w, w3, fmaf(xv.z, w2, fmaf(xv.y, w1, fmaf(xv.x, w0, acc[rr]))));
        }
    }
    float bb = bias[lane];
    #pragma unroll
    for (int rr = 0; rr < 8; ++rr) acc[rr] += bb;

    // fragment-major bf16 store: one short8 (16B) per lane covers e=0..7
    {
        const int ks = r0 >> 5;
        const int n = lane >> 4;
        const int lane_dst = (lane & 15) + (((r0 >> 3) & 3) << 4);
        short8 pk;
        #pragma unroll
        for (int rr = 0; rr < 8; ++rr) pk[rr] = f2bf_bits(acc[rr]);
        *reinterpret_cast<short8*>(hswz + (size_t)((ks * 4 + n) * 64 + lane_dst) * 8) = pk;
    }

    float asrc = a[lane], adst = a[FOUT + lane];
    float ab = a_b[0];
    float ss[8], sd[8];
    #pragma unroll
    for (int rr = 0; rr < 8; ++rr) { ss[rr] = acc[rr] * asrc; sd[rr] = acc[rr] * adst; }
    #pragma unroll
    for (int m = 32; m >= 1; m >>= 1) {
        #pragma unroll
        for (int rr = 0; rr < 8; ++rr) {
            ss[rr] += __shfl_xor(ss[rr], m);
            sd[rr] += __shfl_xor(sd[rr], m);
        }
    }
    if (lane == 0) {
        float4 v0 = { ss[0] + ab, ss[1] + ab, ss[2] + ab, ss[3] + ab };
        float4 v1 = { ss[4] + ab, ss[5] + ab, ss[6] + ab, ss[7] + ab };
        float4 u0 = { sd[0], sd[1], sd[2], sd[3] };
        float4 u1 = { sd[4], sd[5], sd[6], sd[7] };
        *reinterpret_cast<float4*>(s_src + r0)     = v0;
        *reinterpret_cast<float4*>(s_src + r0 + 4) = v1;
        *reinterpret_cast<float4*>(s_dst + r0)     = u0;
        *reinterpret_cast<float4*>(s_dst + r0 + 4) = u1;
    }
}

// Kernel B: block = 16 rows x 8 waves. Block-cooperative slab pipeline:
// stage slab s+1 (32 KB, 16 rows x 512 cols, each DMA = 1 KB contiguous of ONE row)
// -> compute slab s (wave w owns cols [w*64, w*64+64)) -> __syncthreads (full drain).
// XOR swizzle (granule ^= row&7) applied to the GLOBAL source; LDS dest linear;
// same XOR on the ds_read address (rule: both-sides-or-neither).
__global__ __launch_bounds__(512) void gat_attn(
    const int* __restrict__ adj,
    const float* __restrict__ s_src,
    const float* __restrict__ s_dst,
    const unsigned short* __restrict__ hswz,
    float* __restrict__ out)
{
    __shared__ __align__(16) char smem[65536];   // 2 x 32KB slab buffers; epilogue overlays

    const int lane = threadIdx.x & 63;
    const int wave = threadIdx.x >> 6;
    const int i0 = blockIdx.x * 16;
    const int r = lane & 15;
    const int ko = (lane >> 4) * 8;

    const float ssrc = s_src[i0 + r];
    floatx4 acc[4] = { {0.f,0.f,0.f,0.f},{0.f,0.f,0.f,0.f},
                       {0.f,0.f,0.f,0.f},{0.f,0.f,0.f,0.f} };
    float denom = 0.f;

    char* buf0 = smem;
    char* buf1 = smem + 32768;

    // stage slab s: wave w DMAs rows 2w, 2w+1 (2 halves each = 4 x 1KB)
    auto stage = [&](char* buf, int s) {
        #pragma unroll
        for (int q = 0; q < 4; ++q) {
            const int row = wave * 2 + (q >> 1);
            const int half = q & 1;
            const int* g = adj + (size_t)(i0 + row) * N_NODES + s * SLAB
                         + half * 256 + ((lane ^ (row & 7)) << 2);
            __builtin_amdgcn_global_load_lds(
                (const __attribute__((address_space(1))) int*)g,
                (__attribute__((address_space(3))) int*)(buf + row * 2048 + half * 1024),
                16, 0, 0);
        }
    };

    stage(buf0, 0);
    __syncthreads();

    for (int s = 0; s < NSLAB; ++s) {
        const char* cur = (s & 1) ? buf1 : buf0;
        char* nxt = (s & 1) ? buf0 : buf1;
        if (s + 1 < NSLAB) stage(nxt, s + 1);

        const int rbase = r * 2048;
        #pragma unroll
        for (int kk = 0; kk < 2; ++kk) {
            const int c0 = wave * 64 + kk * 32 + ko;          // col in slab, 0..511
            const int hb = (c0 >> 8) << 10;                   // half base (bytes)
            const int c = c0 & 255;                           // col within half
            const int g0 = (((c >> 2) + 0) ^ (r & 7)) << 4;   // 16B granule, swizzled
            const int g1 = (((c >> 2) + 1) ^ (r & 7)) << 4;
            int4 A0 = *reinterpret_cast<const int4*>(cur + rbase + hb + g0);
            int4 A1 = *reinterpret_cast<const int4*>(cur + rbase + hb + g1);
            const int jb = s * SLAB + c0;
            float4 S0 = *reinterpret_cast<const float4*>(s_dst + jb);
            float4 S1 = *reinterpret_cast<const float4*>(s_dst + jb + 4);
            float p0 = pval(ssrc, S0.x, A0.x);
            float p1 = pval(ssrc, S0.y, A0.y);
            float p2 = pval(ssrc, S0.z, A0.z);
            float p3 = pval(ssrc, S0.w, A0.w);
            float p4 = pval(ssrc, S1.x, A1.x);
            float p5 = pval(ssrc, S1.y, A1.y);
            float p6 = pval(ssrc, S1.z, A1.z);
            float p7 = pval(ssrc, S1.w, A1.w);
            denom += ((p0 + p1) + (p2 + p3)) + ((p4 + p5) + (p6 + p7));
            short8 af;
            af[0] = f2bf_bits(p0); af[1] = f2bf_bits(p1);
            af[2] = f2bf_bits(p2); af[3] = f2bf_bits(p3);
            af[4] = f2bf_bits(p4); af[5] = f2bf_bits(p5);
            af[6] = f2bf_bits(p6); af[7] = f2bf_bits(p7);
            const int ks = (jb >> 5);                          // = s*16 + wave*2 + kk
            #pragma unroll
            for (int n = 0; n < 4; ++n) {
                short8 bf = *reinterpret_cast<const short8*>(
                    hswz + (size_t)((ks * 4 + n) * 64 + lane) * 8);
                acc[n] = __builtin_amdgcn_mfma_f32_16x16x32_bf16(af, bf, acc[n], 0, 0, 0);
            }
        }
        __syncthreads();   // drains this wave's stage DMAs + barriers buffer swap
    }

    // reduce denom over the 4 ko-groups (lanes sharing lane&15)
    denom += __shfl_xor(denom, 16);
    denom += __shfl_xor(denom, 32);

    // loop's trailing __syncthreads guarantees all waves are done with LDS tiles
    floatx4* redbuf = (floatx4*)smem;          // [8][4][64] = 32 KB
    float* dred = (float*)(smem + 32768);      // [8][16]
    #pragma unroll
    for (int n = 0; n < 4; ++n) redbuf[(wave * 4 + n) * 64 + lane] = acc[n];
    if (lane < 16) dred[wave * 16 + lane] = denom;
    __syncthreads();

    if (wave < 4) {
        floatx4 facc = redbuf[wave * 64 + lane];
        #pragma unroll
        for (int v = 1; v < 8; ++v) facc += redbuf[(v * 4 + wave) * 64 + lane];
        #pragma unroll
        for (int e = 0; e < 4; ++e) {
            const int r2 = (lane >> 4) * 4 + e;
            float dn = 0.f;
            #pragma unroll
            for (int v = 0; v < 8; ++v) dn += dred[v * 16 + r2];
            float val = facc[e] / dn;
            val = val > 0.f ? val : (__expf(val) - 1.f);   // ELU
            out[(size_t)(i0 + r2) * FOUT + wave * 16 + (lane & 15)] = val;
        }
    }
}

extern "C" void kernel_launch(void* const* d_in, const int* in_sizes, int n_in,
                              void* d_out, int out_size, void* d_ws, size_t ws_size,
                              hipStream_t stream) {
    const float* x   = (const float*)d_in[0];
    const int*   adj = (const int*)d_in[1];
    const float* W   = (const float*)d_in[2];
    const float* b   = (const float*)d_in[3];
    const float* a   = (const float*)d_in[4];
    const float* a_b = (const float*)d_in[5];
    float* out = (float*)d_out;

    char* ws = (char*)d_ws;
    float* s_src = (float*)ws;                                 // 32 KB
    float* s_dst = (float*)(ws + 32 * 1024);                   // 32 KB
    unsigned short* hswz = (unsigned short*)(ws + 64 * 1024);  // 1 MB

    hipLaunchKernelGGL(gat_h, dim3(N_NODES / 32), dim3(256), 0, stream,
                       x, W, b, a, a_b, s_src, s_dst, hswz);
    hipLaunchKernelGGL(gat_attn, dim3(N_NODES / 16), dim3(512), 0, stream,
                       adj, s_src, s_dst, hswz, out);
}